// Round 1
// baseline (90.267 us; speedup 1.0000x reference)
//
#include <hip/hip_runtime.h>

#define LL 64
#define NN 20
#define DTC 0.01f
#define NOISEC 1e-3f
#define LN2C 0.69314718056f

typedef __attribute__((ext_vector_type(8))) short short8x;
typedef __attribute__((ext_vector_type(4))) float f32x4;
typedef __attribute__((ext_vector_type(4))) int v4i;

// pack two floats to bf16x2 with round-to-nearest-even (manual, no HIP types)
__device__ __forceinline__ unsigned bf16r(float x) {
    union { float f; unsigned u; } a; a.f = x;
    return (a.u + (0x7fffu + ((a.u >> 16) & 1u))) >> 16;
}
__device__ __forceinline__ unsigned pk_bf16(float x, float y) {
    return bf16r(x) | (bf16r(y) << 16);
}

// Single-step row_shr:D (D=1..15), bound_ctrl zero-fill, applied to all 4
// dwords of a bf16x8 fragment. Bv[d](nh,qd) = Bv[0](nh-d,qd), 0 for nh<d.
// R13: replaces the 15-deep serial row_shr:1 chain with 15 INDEPENDENT ops.
template<int CTRL>
__device__ __forceinline__ short8x dpp_shr(short8x v) {
    v4i p = __builtin_bit_cast(v4i, v);
    v4i q;
    q.x = __builtin_amdgcn_update_dpp(0, p.x, CTRL, 0xf, 0xf, true);
    q.y = __builtin_amdgcn_update_dpp(0, p.y, CTRL, 0xf, 0xf, true);
    q.z = __builtin_amdgcn_update_dpp(0, p.z, CTRL, 0xf, 0xf, true);
    q.w = __builtin_amdgcn_update_dpp(0, p.w, CTRL, 0xf, 0xf, true);
    return __builtin_bit_cast(short8x, q);
}

// R13: TWO waves (128 thr) per channel c = b*64+l, M-tile split:
//   wave 0 -> output tile 0 (A at baseA-32d),      writes pdst[dstw]
//   wave 1 -> output tile 1 (A at baseA-32d-16),   writes pdst[dstw+16]
// Rationale: previous version was 1 wave/SIMD (Occupancy 7.8%, all pipes
// idle, latency-bound). Split doubles waves/SIMD to 2 for latency hiding;
// per-wave work halves (16 ds_read_b128 + 16 MFMA). One __syncthreads per
// step carries the Qn-write -> next-step B/A-read dependency across waves.
// Block-Toeplitz MFMA (validated R8/R9): Qn[32I+i] = sum_d sum_k
// G_d[i][k]*Qsrc[32(I-d)+k], G_d[i][k] = g(32d+i-k), g = DT*q_n reversed,
// zero for negative arg. gt copy kk pos w holds r[w+kk] so every A-read is
// one aligned ds_read_b128. B-fragments for d>=1 derived from Bv[0] via
// independent DPP row_shr:d (bound_ctrl zeros give the I-d<0 boundary).
__global__ __launch_bounds__(128, 2) void outage_kernel(
    const float* __restrict__ pathloss,
    const float* __restrict__ powers,
    float* __restrict__ out)
{
    __shared__ __align__(16) unsigned short gt[2][8][544];  // 8 shifted copies, ping-pong
    __shared__ __align__(16) unsigned short Qb[2][1024];    // [0,512)=zeros, [512,1024)=data

    const int lane = threadIdx.x & 63;
    const int wid  = threadIdx.x >> 6;     // 0: tile 0 (+fill_g), 1: tile 1 (+loss)
    const int c = blockIdx.x, b = c >> 6, l = c & 63;
    const int nh = lane & 15;              // MFMA m / n index
    const int qd = lane >> 4;              // MFMA quad (k-group)

    // ---- inline prep: rowsum + diag of pathloss row l (both waves) ----
    const float pl = pathloss[l * LL + lane];
    float rs = pl;
    #pragma unroll
    for (int mk = 1; mk < 64; mk <<= 1) rs += __shfl_xor(rs, mk, 64);
    const float dg   = __shfl(pl, l, 64);
    const float dsum = rs - dg;

    // per-lane time constants, tau = 8*lane + u
    float P2[8], P1[8];
    #pragma unroll
    for (int u = 0; u < 8; ++u) {
        P2[u] = exp2f((8 * lane + u) * DTC);
        P1[u] = P2[u] - 1.f;
    }

    // zero prefixes / tails, split across waves
    if (wid == 0) {
        *((uint4*)&Qb[0][0] + lane) = uint4{0u, 0u, 0u, 0u};
    } else {
        *((uint4*)&Qb[1][0] + lane) = uint4{0u, 0u, 0u, 0u};
        const int bb = lane >> 5, w = lane & 31;
        #pragma unroll
        for (int k = 0; k < 8; ++k) gt[bb][k][512 + w] = 0;
    }

    // Q0(tau) = 1 - exp(-(2^{tau*DT}-1)*s0); both waves compute (wave 1
    // keeps q7 for the loss), wave 0 stores bf16 into Qb[0]
    const float p0 = powers[(b * NN + 0) * LL + l];
    const float s0 = dg * p0 / (p0 * dsum + NOISEC);
    float q7;
    {
        float v[8];
        #pragma unroll
        for (int u = 0; u < 8; ++u) v[u] = 1.f - expf(-P1[u] * s0);
        q7 = v[7];                                  // lane 63: Q0[511]
        if (wid == 0) {
            uint4 d4 = { pk_bf16(v[0], v[1]), pk_bf16(v[2], v[3]),
                         pk_bf16(v[4], v[5]), pk_bf16(v[6], v[7]) };
            *(uint4*)&Qb[0][512 + 8 * lane] = d4;
        }
    }

    const float p1v = powers[(b * NN + 1) * LL + l];
    float lossCh = 1.f + p0 + (p1v + 1.f) * q7;     // only wave1 lane63's is used

    // fill the 8 shifted copies of r[tau] = DT*q_n(tau) for a step into buf
    auto fill_g = [&](int buf, float p) {
        float s  = dg * p / (p * dsum + NOISEC);
        float cm = s * LN2C * DTC;
        unsigned F[8];                               // F[0..3] own pairs, F[4..7] neighbor
        #pragma unroll
        for (int w = 0; w < 4; ++w) {
            float a  = expf(-P1[2 * w] * s) * P2[2 * w] * cm;
            float bb = expf(-P1[2 * w + 1] * s) * P2[2 * w + 1] * cm;
            F[w] = pk_bf16(a, bb);
        }
        #pragma unroll
        for (int w = 0; w < 4; ++w) {
            unsigned t = (unsigned)__shfl_down((int)F[w], 1, 64);
            F[4 + w] = (lane == 63) ? 0u : t;       // tau >= 512 -> 0
        }
        unsigned E[7];                               // odd-phase pairs
        #pragma unroll
        for (int j = 0; j < 7; ++j) E[j] = (F[j] >> 16) | (F[j + 1] << 16);
        #pragma unroll
        for (int k = 0; k < 8; ++k) {               // copy k pos 8L+w holds r[8L+w+k]
            uint4 d4;
            if ((k & 1) == 0) d4 = uint4{F[k / 2], F[k / 2 + 1], F[k / 2 + 2], F[k / 2 + 3]};
            else              d4 = uint4{E[k / 2], E[k / 2 + 1], E[k / 2 + 2], E[k / 2 + 3]};
            *(uint4*)&gt[buf][k][8 * lane] = d4;
        }
    };
    if (wid == 0) fill_g(1, p1v);                   // g-table for step n=1

    const int kk    = (7 - nh) & 7;                 // this lane's copy index
    const int baseA = 511 - nh + 8 * qd - kk;       // == 0 mod 8 (16B aligned)
    const int aoff  = baseA - (wid << 4);           // wave1: tile-1 shift (-16)
    const int baseB = 512 + 32 * nh + 8 * qd;
    const int dstw  = 512 + 32 * nh + 4 * qd + (wid << 4);

    float pnext = powers[(b * NN + 2) * LL + l];    // pw[n+1] entering n=1

    __syncthreads();                                // init stores visible to both waves

    for (int n = 1; n < NN; ++n) {
        const unsigned short* psrc = &Qb[(n + 1) & 1][0];   // == (n-1)&1
        const unsigned short* pg   = &gt[n & 1][kk][0];
        unsigned short* pdst       = &Qb[n & 1][0];

        // issue next-next power load early (lands during this step's work)
        float pfut = 0.f;
        if (n <= NN - 3) pfut = powers[(b * NN + n + 2) * LL + l];

        // ---- B: one ds_read_b128 + 15 INDEPENDENT row_shr:d derivations ----
        short8x Bv[16];
        Bv[0]  = *(const short8x*)&psrc[baseB];
        Bv[1]  = dpp_shr<0x111>(Bv[0]);
        Bv[2]  = dpp_shr<0x112>(Bv[0]);
        Bv[3]  = dpp_shr<0x113>(Bv[0]);
        Bv[4]  = dpp_shr<0x114>(Bv[0]);
        Bv[5]  = dpp_shr<0x115>(Bv[0]);
        Bv[6]  = dpp_shr<0x116>(Bv[0]);
        Bv[7]  = dpp_shr<0x117>(Bv[0]);
        Bv[8]  = dpp_shr<0x118>(Bv[0]);
        Bv[9]  = dpp_shr<0x119>(Bv[0]);
        Bv[10] = dpp_shr<0x11A>(Bv[0]);
        Bv[11] = dpp_shr<0x11B>(Bv[0]);
        Bv[12] = dpp_shr<0x11C>(Bv[0]);
        Bv[13] = dpp_shr<0x11D>(Bv[0]);
        Bv[14] = dpp_shr<0x11E>(Bv[0]);
        Bv[15] = dpp_shr<0x11F>(Bv[0]);

        // ---- A operands: this wave's tile only (16 x ds_read_b128) ----
        short8x Av[16];
        #pragma unroll
        for (int d = 0; d < 16; ++d) Av[d] = *(const short8x*)&pg[aoff - 32 * d];

        // ---- wave0 fills the g-table for step n+1 under the MFMA shadow ----
        if (wid == 0 && n < NN - 1) fill_g((n + 1) & 1, pnext);

        // ---- 4 independent MFMA chains (d mod 4), 4 deep each ----
        f32x4 a0 = {0.f, 0.f, 0.f, 0.f}, a1 = {0.f, 0.f, 0.f, 0.f};
        f32x4 a2 = {0.f, 0.f, 0.f, 0.f}, a3 = {0.f, 0.f, 0.f, 0.f};
        #pragma unroll
        for (int d = 0; d < 16; d += 4) {
            a0 = __builtin_amdgcn_mfma_f32_16x16x32_bf16(Av[d],     Bv[d],     a0, 0, 0, 0);
            a1 = __builtin_amdgcn_mfma_f32_16x16x32_bf16(Av[d + 1], Bv[d + 1], a1, 0, 0, 0);
            a2 = __builtin_amdgcn_mfma_f32_16x16x32_bf16(Av[d + 2], Bv[d + 2], a2, 0, 0, 0);
            a3 = __builtin_amdgcn_mfma_f32_16x16x32_bf16(Av[d + 3], Bv[d + 3], a3, 0, 0, 0);
        }
        f32x4 acc = (a0 + a1) + (a2 + a3);

        // write Qn (bf16): lane holds rows 4qd..4qd+3 of its M-tile, col nh
        *(uint2*)&pdst[dstw] = uint2{pk_bf16(acc.x, acc.y), pk_bf16(acc.z, acc.w)};

        // loss tap: wave1 lane63 acc.w == Qn[511] (row 31, col 15), fp32
        if (wid == 1) {
            float wgt = (n < NN - 1) ? (pnext + 1.f) : 1.f;   // pnext == pw[n+1]
            lossCh += wgt * acc.w;
        }
        pnext = pfut;

        __syncthreads();    // Qn + g-table(n+1) visible before next step reads
    }

    if (wid == 1 && lane == 63) atomicAdd(out, lossCh);
}

extern "C" void kernel_launch(void* const* d_in, const int* in_sizes, int n_in,
                              void* d_out, int out_size, void* d_ws, size_t ws_size,
                              hipStream_t stream) {
    const float* pathloss = (const float*)d_in[0];
    const float* powers   = (const float*)d_in[1];
    float* outp = (float*)d_out;

    (void)hipMemsetAsync(d_out, 0, sizeof(float) * out_size, stream);
    outage_kernel<<<16 * LL, 128, 0, stream>>>(pathloss, powers, outp);
}